// Round 4
// baseline (127.207 us; speedup 1.0000x reference)
//
#include <hip/hip_runtime.h>
#include <hip/hip_bf16.h>
#include <math.h>

#define MUL 8
#define HID 16
#define NB 10

// Kernel A: zero out; build scaled reduced weights in d_ws:
//   ws[0..511]  = W2red[j][cu] = group_scale(c) * 0.0625 * sum_v W2[j][cu*8+v]
//   ws[512..671] = W1s = sqrt(2) * W1
__global__ void prep_kernel(const float* __restrict__ W2,
                            const float* __restrict__ W1,
                            float* __restrict__ ws,
                            float* __restrict__ out) {
    int t = threadIdx.x;
    if (t == 0) out[0] = 0.0f;
    if (t < HID * 32) {
        int j  = t >> 5;
        int cu = t & 31;
        int c  = cu >> 3;
        const float pw0 = 0.25f;            // sqrt(1/16)
        const float pw1 = 0.43301270189f;   // sqrt(3/16)
        const float i3  = 0.57735026919f;   // 1/sqrt(3)
        float gs = (c < 2) ? pw0 : ((c == 2) ? pw1 : pw1 * i3);
        const float* p = W2 + j * 256 + cu * 8;
        float s = 0.0f;
#pragma unroll
        for (int v = 0; v < 8; ++v) s += p[v];
        ws[t] = s * 0.0625f * gs;
    }
    if (t < NB * HID) ws[512 + t] = W1[t] * 1.41421356237f;
}

// Kernel A2: convert node features f32 -> packed bf16 (2 per uint).
// Shrinks the gather table 6.4 MB -> 3.2 MB (~ per-XCD L2) and halves
// divergent gather bytes per edge (128 B -> 64 B).
__global__ __launch_bounds__(256) void conv_kernel(const float* __restrict__ X,
                                                   unsigned* __restrict__ Xb,
                                                   int nPack) {
    int i = blockIdx.x * 256 + threadIdx.x;
    if (i < nPack) {
        float2 f = ((const float2*)X)[i];
        __hip_bfloat16 a = __float2bfloat16(f.x);
        __hip_bfloat16 b = __float2bfloat16(f.y);
        unsigned ua = *reinterpret_cast<unsigned short*>(&a);
        unsigned ub = *reinterpret_cast<unsigned short*>(&b);
        Xb[i] = ua | (ub << 16);
    }
}

// basis + hidden layer: depends only on r
__device__ __forceinline__ void basis_h(float r, const float* __restrict__ W1s,
                                        float h[HID]) {
    const float inv_step = 11.0f / 3.0f;   // step = 3/11
    float q = r * inv_step;
    int qi = (int)floorf(q);
    int ia = qi - 1, ib = qi;
    float diffa = q - (float)(ia + 1);     // [0,1)
    float diffb = q - (float)(ib + 1);     // [-1,0)
    float dena = 1.0f - diffa * diffa;     // (0,1]
    float denb = 1.0f - diffb * diffb;     // [0,1]; 0 -> exp(-inf)=0
    bool va = (ia >= 0) & (ia < NB);
    bool vb = (ib >= 0) & (ib < NB);
    float fa = va ? 1.14136f * __expf(2.0f - 2.0f / dena) : 0.0f;
    float fb = vb ? 1.14136f * __expf(2.0f - 2.0f / denb) : 0.0f;
    int ica = min(max(ia, 0), NB - 1);
    int icb = min(max(ib, 0), NB - 1);
    const float* ra = W1s + ica * HID;
    const float* rb = W1s + icb * HID;
#pragma unroll
    for (int j = 0; j < HID; ++j) {
        float a = fa * ra[j] + fb * rb[j];
        h[j] = (a > 0.0f) ? a : 0.0f;
    }
}

// contraction: weights via uniform-offset global reads -> s_load / SGPR ops
__device__ __forceinline__ float edge_acc(const float h[HID], const float s[MUL],
                                          const float d[MUL], const float V[MUL],
                                          float U, const float* __restrict__ W2r) {
    float acc = 0.0f;
#pragma unroll
    for (int j = 0; j < HID; ++j) {
        const float* w = W2r + j * 32;
        float A = 0.0f, B = 0.0f, C = 0.0f, D = 0.0f;
#pragma unroll
        for (int u = 0; u < MUL; ++u) {
            A += w[u]      * s[u];
            B += w[8 + u]  * d[u];
            C += w[16 + u] * s[u];
            D += w[24 + u] * V[u];
        }
        acc += h[j] * (A + B + U * C + D);
    }
    return acc;
}

#define UNP(u, lo, hi) { lo = __uint_as_float((u) << 16); hi = __uint_as_float((u) & 0xffff0000u); }

// Kernel B (bf16 table): one edge per thread, 4x uint4 divergent gather.
__global__ __launch_bounds__(256, 6) void edge_kernel_bf16(
    const unsigned* __restrict__ Xb,  // N x 16 uints (32 bf16)
    const float* __restrict__ EV,     // E x 3
    const int*   __restrict__ SRC,    // E
    const float* __restrict__ W2r,    // 16 x 32 scaled
    const float* __restrict__ W1s,    // 10 x 16 scaled
    float* __restrict__ out, int E)
{
    int tid = threadIdx.x;
    int e = blockIdx.x * 256 + tid;
    float contrib = 0.0f;
    if (e < E) {
        int si = SRC[e];
        const uint4* xp = (const uint4*)(Xb + (size_t)si * 16);
        uint4 q0 = xp[0], q1 = xp[1], q2 = xp[2], q3 = xp[3];

        float ex = EV[3 * e], ey = EV[3 * e + 1], ez = EV[3 * e + 2];
        float r = sqrtf(ex * ex + ey * ey + ez * ez);
        float ir = 1.0f / r;
        float ux = ex * ir, uy = ey * ir, uz = ez * ir;
        float U = ux + uy + uz;
        float h[HID];
        basis_h(r, W1s, h);

        float s[MUL], vv[24];
        UNP(q0.x, s[0], s[1]); UNP(q0.y, s[2], s[3]);
        UNP(q0.z, s[4], s[5]); UNP(q0.w, s[6], s[7]);
        UNP(q1.x, vv[0], vv[1]);   UNP(q1.y, vv[2], vv[3]);
        UNP(q1.z, vv[4], vv[5]);   UNP(q1.w, vv[6], vv[7]);
        UNP(q2.x, vv[8], vv[9]);   UNP(q2.y, vv[10], vv[11]);
        UNP(q2.z, vv[12], vv[13]); UNP(q2.w, vv[14], vv[15]);
        UNP(q3.x, vv[16], vv[17]); UNP(q3.y, vv[18], vv[19]);
        UNP(q3.z, vv[20], vv[21]); UNP(q3.w, vv[22], vv[23]);

        float d[MUL], V[MUL];
#pragma unroll
        for (int u = 0; u < MUL; ++u) {
            float vx = vv[3 * u], vy = vv[3 * u + 1], vz = vv[3 * u + 2];
            d[u] = vx * ux + vy * uy + vz * uz;
            V[u] = vx + vy + vz;
        }
        contrib = edge_acc(h, s, d, V, U, W2r);
    }

#pragma unroll
    for (int off = 32; off > 0; off >>= 1)
        contrib += __shfl_down(contrib, off, 64);
    __shared__ float wsum[4];
    int lane = tid & 63, w = tid >> 6;
    if (lane == 0) wsum[w] = contrib;
    __syncthreads();
    if (tid == 0) {
        float ssum = wsum[0] + wsum[1] + wsum[2] + wsum[3];
        atomicAdd(out, ssum);
    }
}

// Kernel B fallback (f32 table, R2 structure) if ws too small for Xb.
__global__ __launch_bounds__(256, 6) void edge_kernel_f32(
    const float* __restrict__ X,
    const float* __restrict__ EV,
    const int*   __restrict__ SRC,
    const float* __restrict__ W2r,
    const float* __restrict__ W1s,
    float* __restrict__ out, int E)
{
    int tid = threadIdx.x;
    int e = blockIdx.x * 256 + tid;
    float contrib = 0.0f;
    if (e < E) {
        int si = SRC[e];
        const float4* xp = (const float4*)(X + (size_t)si * 32);
        float4 x[8];
#pragma unroll
        for (int k = 0; k < 8; ++k) x[k] = xp[k];
        float ex = EV[3 * e], ey = EV[3 * e + 1], ez = EV[3 * e + 2];
        float r = sqrtf(ex * ex + ey * ey + ez * ez);
        float ir = 1.0f / r;
        float ux = ex * ir, uy = ey * ir, uz = ez * ir;
        float U = ux + uy + uz;
        float h[HID];
        basis_h(r, W1s, h);
        float s[MUL] = {x[0].x, x[0].y, x[0].z, x[0].w,
                        x[1].x, x[1].y, x[1].z, x[1].w};
        float vv[24];
#pragma unroll
        for (int k = 0; k < 6; ++k) {
            vv[4 * k + 0] = x[2 + k].x; vv[4 * k + 1] = x[2 + k].y;
            vv[4 * k + 2] = x[2 + k].z; vv[4 * k + 3] = x[2 + k].w;
        }
        float d[MUL], V[MUL];
#pragma unroll
        for (int u = 0; u < MUL; ++u) {
            float vx = vv[3 * u], vy = vv[3 * u + 1], vz = vv[3 * u + 2];
            d[u] = vx * ux + vy * uy + vz * uz;
            V[u] = vx + vy + vz;
        }
        contrib = edge_acc(h, s, d, V, U, W2r);
    }
#pragma unroll
    for (int off = 32; off > 0; off >>= 1)
        contrib += __shfl_down(contrib, off, 64);
    __shared__ float wsum[4];
    int lane = tid & 63, w = tid >> 6;
    if (lane == 0) wsum[w] = contrib;
    __syncthreads();
    if (tid == 0) {
        float ssum = wsum[0] + wsum[1] + wsum[2] + wsum[3];
        atomicAdd(out, ssum);
    }
}

extern "C" void kernel_launch(void* const* d_in, const int* in_sizes, int n_in,
                              void* d_out, int out_size, void* d_ws, size_t ws_size,
                              hipStream_t stream) {
    const float* X   = (const float*)d_in[0];
    const float* EV  = (const float*)d_in[1];
    const float* W1  = (const float*)d_in[2];
    const float* W2  = (const float*)d_in[3];
    const int*   SRC = (const int*)d_in[4];
    int E = in_sizes[4];
    int N = in_sizes[0] / 32;

    float* ws  = (float*)d_ws;   // [W2red 512 f32][W1s 160 f32][Xb N*16 uints]
    float* out = (float*)d_out;

    prep_kernel<<<1, 512, 0, stream>>>(W2, W1, ws, out);
    int blocks = (E + 255) / 256;
    size_t need = 2688 + (size_t)N * 64;
    if (ws_size >= need) {
        unsigned* Xb = (unsigned*)((char*)d_ws + 2688);
        int nPack = N * 16;
        conv_kernel<<<(nPack + 255) / 256, 256, 0, stream>>>(X, Xb, nPack);
        edge_kernel_bf16<<<blocks, 256, 0, stream>>>(Xb, EV, SRC, ws, ws + 512, out, E);
    } else {
        edge_kernel_f32<<<blocks, 256, 0, stream>>>(X, EV, SRC, ws, ws + 512, out, E);
    }
}

// Round 5
// 97.220 us; speedup vs baseline: 1.3084x; 1.3084x over previous
//
#include <hip/hip_runtime.h>
#include <math.h>

#define MUL 8
#define HID 16
#define NB 10

typedef short short8 __attribute__((ext_vector_type(8)));
typedef float floatx4 __attribute__((ext_vector_type(4)));

__device__ __forceinline__ short f2bf(float x) {
    unsigned u = __float_as_uint(x);
    unsigned r = (u + 0x7fffu + ((u >> 16) & 1u)) >> 16;  // RNE
    return (short)r;
}

// ws layout (floats): [0..511] W2r scaled | [512..671] W1s | [672..735] partials
// | [736.. ] Xb (bf16-packed node table, 16B aligned: 736*4 = 2944)
__global__ void prep_kernel(const float* __restrict__ W2,
                            const float* __restrict__ W1,
                            float* __restrict__ ws) {
    int t = threadIdx.x;
    if (t < 64) ws[672 + t] = 0.0f;
    if (t < HID * 32) {
        int j  = t >> 5;
        int cu = t & 31;
        int c  = cu >> 3;
        const float pw0 = 0.25f;            // sqrt(1/16)
        const float pw1 = 0.43301270189f;   // sqrt(3/16)
        const float i3  = 0.57735026919f;   // 1/sqrt(3)
        float gs = (c < 2) ? pw0 : ((c == 2) ? pw1 : pw1 * i3);
        const float* p = W2 + j * 256 + cu * 8;
        float s = 0.0f;
#pragma unroll
        for (int v = 0; v < 8; ++v) s += p[v];
        ws[t] = s * 0.0625f * gs;           // 1/sqrt(HID) * 1/sqrt(16)
    }
    if (t < NB * HID) ws[512 + t] = W1[t] * 1.41421356237f;
}

// f32 -> packed bf16 node table (6.4 MB -> 3.2 MB, ~L2-resident)
__global__ __launch_bounds__(256) void conv_kernel(const float* __restrict__ X,
                                                   unsigned* __restrict__ Xb,
                                                   int nPack) {
    int i = blockIdx.x * 256 + threadIdx.x;
    if (i < nPack) {
        float2 f = ((const float2*)X)[i];
        unsigned a = (unsigned)(unsigned short)f2bf(f.x);
        unsigned b = (unsigned)(unsigned short)f2bf(f.y);
        Xb[i] = a | (b << 16);
    }
}

#define UNP(u, lo, hi) { lo = __uint_as_float((u) << 16); hi = __uint_as_float((u) & 0xffff0000u); }

// Each wave: 64 edges. Per-lane compute h[16], f[32]; transpose through
// XOR-swizzled LDS into MFMA fragments; M += h x f via 4 MFMAs; weights
// applied ONCE per wave in the epilogue (no per-edge weight loads at all).
__global__ __launch_bounds__(256, 4) void edge_kernel(
    const unsigned* __restrict__ Xb,   // N x 16 uints (32 bf16)
    const float* __restrict__ EV,      // E x 3
    const int*   __restrict__ SRC,     // E
    const float* __restrict__ W2r,     // 16 x 32 scaled
    const float* __restrict__ W1s,     // 10 x 16 scaled
    float* __restrict__ partial, int E)
{
    __shared__ short A_lds[4][16][64];  // [wave][j][kk]  (xor-swizzled units)
    __shared__ short B_lds[4][32][64];  // [wave][n][kk]
    int tid = threadIdx.x;
    int w = tid >> 6, l = tid & 63;
    int e0 = blockIdx.x * 256 + tid;
    bool valid = (e0 < E);
    int e = valid ? e0 : 0;

    int   si = __builtin_nontemporal_load(SRC + e);
    float ex = __builtin_nontemporal_load(EV + 3 * e);
    float ey = __builtin_nontemporal_load(EV + 3 * e + 1);
    float ez = __builtin_nontemporal_load(EV + 3 * e + 2);
    const uint4* xp = (const uint4*)(Xb + (size_t)si * 16);
    uint4 q0 = xp[0], q1 = xp[1], q2 = xp[2], q3 = xp[3];

    float r = sqrtf(ex * ex + ey * ey + ez * ez);
    float ir = 1.0f / r;
    float ux = ex * ir, uy = ey * ir, uz = ez * ir;
    float U = ux + uy + uz;

    // 2-sparse soft one-hot -> h (masked to 0 for invalid lanes)
    const float inv_step = 11.0f / 3.0f;
    float qq = r * inv_step;
    int qi = (int)floorf(qq);
    int ia = qi - 1, ib = qi;
    float diffa = qq - (float)(ia + 1);
    float diffb = qq - (float)(ib + 1);
    float dena = 1.0f - diffa * diffa;
    float denb = 1.0f - diffb * diffb;
    bool va = (ia >= 0) & (ia < NB) & valid;
    bool vb = (ib >= 0) & (ib < NB) & valid;
    float fa = va ? 1.14136f * __expf(2.0f - 2.0f / dena) : 0.0f;
    float fb = vb ? 1.14136f * __expf(2.0f - 2.0f / denb) : 0.0f;
    int ica = min(max(ia, 0), NB - 1);
    int icb = min(max(ib, 0), NB - 1);
    const float* ra = W1s + ica * HID;
    const float* rb = W1s + icb * HID;

    // write A column (this lane's edge) : A[j][kk=l], swizzled
#pragma unroll
    for (int j = 0; j < HID; ++j) {
        float a = fa * ra[j] + fb * rb[j];
        float hj = (a > 0.0f) ? a : 0.0f;
        A_lds[w][j][((((l >> 3) ^ (j & 7)) << 3) | (l & 7))] = f2bf(hj);
    }

    // features: f[0..7]=s (exact bf16 bits), f[8..15]=d, f[16..23]=s*U, f[24..31]=V
    float s[8], vv[24];
    UNP(q0.x, s[0], s[1]); UNP(q0.y, s[2], s[3]);
    UNP(q0.z, s[4], s[5]); UNP(q0.w, s[6], s[7]);
    UNP(q1.x, vv[0], vv[1]);   UNP(q1.y, vv[2], vv[3]);
    UNP(q1.z, vv[4], vv[5]);   UNP(q1.w, vv[6], vv[7]);
    UNP(q2.x, vv[8], vv[9]);   UNP(q2.y, vv[10], vv[11]);
    UNP(q2.z, vv[12], vv[13]); UNP(q2.w, vv[14], vv[15]);
    UNP(q3.x, vv[16], vv[17]); UNP(q3.y, vv[18], vv[19]);
    UNP(q3.z, vv[20], vv[21]); UNP(q3.w, vv[22], vv[23]);

    unsigned sq[4] = {q0.x, q0.y, q0.z, q0.w};
#pragma unroll
    for (int u = 0; u < 8; ++u) {
        unsigned bits = (u & 1) ? (sq[u >> 1] >> 16) : (sq[u >> 1] & 0xffffu);
        B_lds[w][u][((((l >> 3) ^ (u & 7)) << 3) | (l & 7))] = (short)bits;
    }
#pragma unroll
    for (int u = 0; u < 8; ++u) {
        float vx = vv[3 * u], vy = vv[3 * u + 1], vz = vv[3 * u + 2];
        float d = vx * ux + vy * uy + vz * uz;
        float V = vx + vy + vz;
        int n1 = 8 + u, n2 = 16 + u, n3 = 24 + u;
        B_lds[w][n1][((((l >> 3) ^ (n1 & 7)) << 3) | (l & 7))] = f2bf(d);
        B_lds[w][n2][((((l >> 3) ^ (n2 & 7)) << 3) | (l & 7))] = f2bf(s[u] * U);
        B_lds[w][n3][((((l >> 3) ^ (n3 & 7)) << 3) | (l & 7))] = f2bf(V);
    }
    __syncthreads();

    // fragments: A[m=ln][k=c*32+q*8+j], B[k][n=ln or ln+16]
    int ln = l & 15, q = l >> 4;
    short8 a0  = *(const short8*)&A_lds[w][ln][(((q)     ^ (ln & 7)) << 3)];
    short8 a1  = *(const short8*)&A_lds[w][ln][(((4 + q) ^ (ln & 7)) << 3)];
    short8 b00 = *(const short8*)&B_lds[w][ln][(((q)     ^ (ln & 7)) << 3)];
    short8 b01 = *(const short8*)&B_lds[w][ln + 16][(((q)     ^ (ln & 7)) << 3)];
    short8 b10 = *(const short8*)&B_lds[w][ln][(((4 + q) ^ (ln & 7)) << 3)];
    short8 b11 = *(const short8*)&B_lds[w][ln + 16][(((4 + q) ^ (ln & 7)) << 3)];

    floatx4 acc0 = {0.f, 0.f, 0.f, 0.f}, acc1 = {0.f, 0.f, 0.f, 0.f};
    acc0 = __builtin_amdgcn_mfma_f32_16x16x32_bf16(a0, b00, acc0, 0, 0, 0);
    acc1 = __builtin_amdgcn_mfma_f32_16x16x32_bf16(a0, b01, acc1, 0, 0, 0);
    acc0 = __builtin_amdgcn_mfma_f32_16x16x32_bf16(a1, b10, acc0, 0, 0, 0);
    acc1 = __builtin_amdgcn_mfma_f32_16x16x32_bf16(a1, b11, acc1, 0, 0, 0);

    // epilogue: elementwise W . M, once per wave.
    // C/D layout: col = lane&15 (=n), row = (lane>>4)*4 + reg (m89-verified)
    float p = 0.0f;
#pragma unroll
    for (int i = 0; i < 4; ++i) {
        int row = q * 4 + i;
        p += acc0[i] * W2r[row * 32 + ln]
           + acc1[i] * W2r[row * 32 + 16 + ln];
    }
#pragma unroll
    for (int off = 32; off > 0; off >>= 1)
        p += __shfl_down(p, off, 64);

    __shared__ float wsum[4];
    if (l == 0) wsum[w] = p;
    __syncthreads();
    if (tid == 0) {
        float t = wsum[0] + wsum[1] + wsum[2] + wsum[3];
        atomicAdd(partial + (blockIdx.x & 63), t);
    }
}

// fallback (ws too small for bf16 table): R4-style per-edge contraction on f32 X
__global__ __launch_bounds__(256, 6) void edge_kernel_f32(
    const float* __restrict__ X, const float* __restrict__ EV,
    const int* __restrict__ SRC, const float* __restrict__ W2r,
    const float* __restrict__ W1s, float* __restrict__ partial, int E)
{
    int tid = threadIdx.x;
    int e = blockIdx.x * 256 + tid;
    float contrib = 0.0f;
    if (e < E) {
        int si = SRC[e];
        const float4* xp = (const float4*)(X + (size_t)si * 32);
        float4 x[8];
#pragma unroll
        for (int k = 0; k < 8; ++k) x[k] = xp[k];
        float ex = EV[3 * e], ey = EV[3 * e + 1], ez = EV[3 * e + 2];
        float r = sqrtf(ex * ex + ey * ey + ez * ez);
        float ir = 1.0f / r;
        float ux = ex * ir, uy = ey * ir, uz = ez * ir;
        float U = ux + uy + uz;
        const float inv_step = 11.0f / 3.0f;
        float qq = r * inv_step;
        int qi = (int)floorf(qq);
        int ia = qi - 1, ib = qi;
        float diffa = qq - (float)(ia + 1), diffb = qq - (float)(ib + 1);
        float dena = 1.0f - diffa * diffa, denb = 1.0f - diffb * diffb;
        bool va = (ia >= 0) & (ia < NB), vb = (ib >= 0) & (ib < NB);
        float fa = va ? 1.14136f * __expf(2.0f - 2.0f / dena) : 0.0f;
        float fb = vb ? 1.14136f * __expf(2.0f - 2.0f / denb) : 0.0f;
        int ica = min(max(ia, 0), NB - 1), icb = min(max(ib, 0), NB - 1);
        const float* ra = W1s + ica * HID;
        const float* rb = W1s + icb * HID;
        float h[HID];
#pragma unroll
        for (int j = 0; j < HID; ++j) {
            float a = fa * ra[j] + fb * rb[j];
            h[j] = (a > 0.0f) ? a : 0.0f;
        }
        float s[8] = {x[0].x, x[0].y, x[0].z, x[0].w, x[1].x, x[1].y, x[1].z, x[1].w};
        float vv[24];
#pragma unroll
        for (int k = 0; k < 6; ++k) {
            vv[4*k+0] = x[2+k].x; vv[4*k+1] = x[2+k].y;
            vv[4*k+2] = x[2+k].z; vv[4*k+3] = x[2+k].w;
        }
        float d[8], V[8];
#pragma unroll
        for (int u = 0; u < 8; ++u) {
            float vx = vv[3*u], vy = vv[3*u+1], vz = vv[3*u+2];
            d[u] = vx*ux + vy*uy + vz*uz; V[u] = vx + vy + vz;
        }
        float acc = 0.0f;
#pragma unroll
        for (int j = 0; j < HID; ++j) {
            const float* wt = W2r + j * 32;
            float A = 0, B = 0, C = 0, D = 0;
#pragma unroll
            for (int u = 0; u < 8; ++u) {
                A += wt[u] * s[u]; B += wt[8+u] * d[u];
                C += wt[16+u] * s[u]; D += wt[24+u] * V[u];
            }
            acc += h[j] * (A + B + U * C + D);
        }
        contrib = acc;
    }
#pragma unroll
    for (int off = 32; off > 0; off >>= 1)
        contrib += __shfl_down(contrib, off, 64);
    __shared__ float wsum[4];
    int lane = tid & 63, w = tid >> 6;
    if (lane == 0) wsum[w] = contrib;
    __syncthreads();
    if (tid == 0)
        atomicAdd(partial + (blockIdx.x & 63), wsum[0] + wsum[1] + wsum[2] + wsum[3]);
}

__global__ void final_kernel(const float* __restrict__ partial,
                             float* __restrict__ out) {
    int t = threadIdx.x;  // 64
    float v = partial[t];
#pragma unroll
    for (int off = 32; off > 0; off >>= 1)
        v += __shfl_down(v, off, 64);
    if (t == 0) out[0] = v;
}

extern "C" void kernel_launch(void* const* d_in, const int* in_sizes, int n_in,
                              void* d_out, int out_size, void* d_ws, size_t ws_size,
                              hipStream_t stream) {
    const float* X   = (const float*)d_in[0];
    const float* EV  = (const float*)d_in[1];
    const float* W1  = (const float*)d_in[2];
    const float* W2  = (const float*)d_in[3];
    const int*   SRC = (const int*)d_in[4];
    int E = in_sizes[4];
    int N = in_sizes[0] / 32;

    float* ws  = (float*)d_ws;
    float* out = (float*)d_out;
    float* partial = ws + 672;

    prep_kernel<<<1, 512, 0, stream>>>(W2, W1, ws);
    int blocks = (E + 255) / 256;
    size_t need = 2944 + (size_t)N * 64;
    if (ws_size >= need) {
        unsigned* Xb = (unsigned*)((char*)d_ws + 2944);
        int nPack = N * 16;
        conv_kernel<<<(nPack + 255) / 256, 256, 0, stream>>>(X, Xb, nPack);
        edge_kernel<<<blocks, 256, 0, stream>>>(Xb, EV, SRC, ws, ws + 512, partial, E);
    } else {
        edge_kernel_f32<<<blocks, 256, 0, stream>>>(X, EV, SRC, ws, ws + 512, partial, E);
    }
    final_kernel<<<1, 64, 0, stream>>>(partial, out);
}